// Round 6
// baseline (862.291 us; speedup 1.0000x reference)
//
#include <hip/hip_runtime.h>

#define NCH 120

typedef int i32x4 __attribute__((ext_vector_type(4)));

// ---------------------------------------------------------------------------
// Prep kernel (1 block, 128 threads): build in ws:
//   [0, 16384): wb_i8[128][128]: rows 0..119 = sign(conv_w) in {-1,0,+1};
//               row 120 = wsum[k] = sum_c sign(conv_w[c][k])  (|.|<=120, fits
//               i8) -> GEMM col 120 yields S1 (row-sum of y) for free;
//               rows 121..127 and cols 120..127 (except row 120's k<120) = 0.
//   [16384, 18432): float4 coef[128] = {conv_b, gn_w, gn_b, lin_w};
//               pads {0,1,0,0} and coef[120].w=0 so col 120 never reaches out.
// ---------------------------------------------------------------------------
__global__ void prep_kernel(const float* __restrict__ conv_w,
                            const float* __restrict__ conv_b,
                            const float* __restrict__ gn_w,
                            const float* __restrict__ gn_b,
                            const float* __restrict__ lin_w,
                            unsigned char* __restrict__ wsb)
{
    const int c = threadIdx.x;            // 0..127 (channel / W row)
    if (c >= 128) return;
    unsigned* row32 = (unsigned*)(wsb + c * 128);
    if (c < NCH) {
        for (int kw = 0; kw < 32; ++kw) {
            unsigned pk = 0u;
            for (int b = 0; b < 4; ++b) {
                const int k = kw * 4 + b;
                unsigned v = 0u;
                if (k < NCH) {
                    const float w = conv_w[c * NCH + k];
                    v = (w > 0.0f) ? 0x01u : ((w < 0.0f) ? 0xFFu : 0x00u);
                }
                pk |= v << (8 * b);
            }
            row32[kw] = pk;
        }
    } else if (c == 120) {
        // column sums of sign(W): the free-S1 row
        for (int kw = 0; kw < 32; ++kw) {
            unsigned pk = 0u;
            for (int b = 0; b < 4; ++b) {
                const int k = kw * 4 + b;
                int s = 0;
                if (k < NCH)
                    for (int r = 0; r < NCH; ++r) {
                        const float w = conv_w[r * NCH + k];
                        s += (w > 0.0f) - (w < 0.0f);
                    }
                pk |= ((unsigned)s & 0xFFu) << (8 * b);
            }
            row32[kw] = pk;
        }
    } else {
        for (int kw = 0; kw < 32; ++kw) row32[kw] = 0u;
    }
    float4 o;
    o.x = (c < NCH) ? conv_b[c] : 0.0f;
    o.y = (c < NCH) ? gn_w[c]   : 1.0f;
    o.z = (c < NCH) ? gn_b[c]   : 0.0f;
    o.w = (c < NCH) ? lin_w[c]  : 0.0f;
    ((float4*)(wsb + 16384))[c] = o;
}

// Binarize 4 floats against 0.5 into 4 packed i8 in {+1, 0, -1}.
// sign(x-0.5): +1 if x>0.5, -1 if x<0.5, 0 if x==0.5 exactly.
__device__ __forceinline__ unsigned cvt4(float4 v) {
    unsigned b0 = (v.x > 0.5f) ? 0x01u : ((v.x < 0.5f) ? 0xFFu : 0x00u);
    unsigned b1 = (v.y > 0.5f) ? 0x01u : ((v.y < 0.5f) ? 0xFFu : 0x00u);
    unsigned b2 = (v.z > 0.5f) ? 0x01u : ((v.z < 0.5f) ? 0xFFu : 0x00u);
    unsigned b3 = (v.w > 0.5f) ? 0x01u : ((v.w < 0.5f) ? 0xFFu : 0x00u);
    return b0 | (b1 << 8) | (b2 << 16) | (b3 << 24);
}

// ---------------------------------------------------------------------------
// Main kernel, v6: i8 MFMA binary GEMM + register prefetch + free S1.
//  - Same verified fragment math as v5 (absmax 0.0039 pass):
//    A: lane holds A[l15][kc*32+lg*8+j]; B likewise from wb[n][k];
//    C: row=lg*4+q, col=l15.
//  - PREFETCH: next tile's 8 float4 loads issue right after the current
//    tile's binarize, overlapping HBM latency (~900cy) with MFMA+epilogue.
//  - S1 comes free from GEMM col 120 (wsum row); only S2 needs the 16-lane
//    xor-butterfly. Col 120 masked out of S2; lin_w[120]=0 keeps it out of d.
// ---------------------------------------------------------------------------
__global__ __launch_bounds__(256) void bnn_kernel(
    const float* __restrict__ x,
    const unsigned char* __restrict__ wsb,
    float* __restrict__ out,
    int B, int num_tiles, int tiles_per_block)
{
    __shared__ float4 s_cf[128];

    const int tid  = threadIdx.x;
    const int lane = tid & 63;
    const int wv   = tid >> 6;
    const int l15  = lane & 15;
    const int lg   = lane >> 4;            // 0..3
    const bool padlane = (lg == 3);        // kc==3 chunk (k=120..127) is pad

    if (tid < 128) s_cf[tid] = ((const float4*)(wsb + 16384))[tid];
    __syncthreads();

    // ---- B fragments: loaded once, kept in VGPRs (8 col-tiles x 4 k-chunks)
    long bfrag[8][4];
#pragma unroll
    for (int t = 0; t < 8; ++t)
#pragma unroll
        for (int kc = 0; kc < 4; ++kc)
            bfrag[t][kc] = *(const long*)(wsb + (t * 16 + l15) * 128 + kc * 32 + lg * 8);

    // ---- prologue: prefetch first tile into pf ----
    float4 pf[8];
    {
        long long srow = (long long)blockIdx.x * 64 + wv * 16 + l15;
        if (srow > (long long)B - 1) srow = (long long)B - 1;
        const float* __restrict__ xr = x + srow * NCH;
#pragma unroll
        for (int j = 0; j < 8; ++j) {
            int off = (j >> 1) * 32 + lg * 8 + (j & 1) * 4;   // floats; 16B-aligned
            if (j >= 6 && padlane) off = (j & 1) * 4;          // pad chunk: safe dummy
            pf[j] = *(const float4*)(xr + off);
        }
    }

    for (int it = 0; it < tiles_per_block; ++it) {
        const int tile = blockIdx.x + it * gridDim.x;
        if (tile >= num_tiles) break;
        const long long s0 = (long long)tile * 64 + wv * 16;

        // ---- binarize the prefetched tile -> A fragments ----
        long afrag[4];
#pragma unroll
        for (int kc = 0; kc < 4; ++kc) {
            unsigned w0 = cvt4(pf[kc * 2]);
            unsigned w1 = cvt4(pf[kc * 2 + 1]);
            if (kc == 3 && padlane) { w0 = 0u; w1 = 0u; }
            afrag[kc] = (long)(((unsigned long long)w1 << 32) | w0);
        }

        // ---- prefetch NEXT tile (overlaps MFMA + epilogue below) ----
        if (it + 1 < tiles_per_block) {
            int nt = blockIdx.x + (it + 1) * gridDim.x;
            if (nt > num_tiles - 1) nt = num_tiles - 1;
            long long srow = (long long)nt * 64 + wv * 16 + l15;
            if (srow > (long long)B - 1) srow = (long long)B - 1;
            const float* __restrict__ xr = x + srow * NCH;
#pragma unroll
            for (int j = 0; j < 8; ++j) {
                int off = (j >> 1) * 32 + lg * 8 + (j & 1) * 4;
                if (j >= 6 && padlane) off = (j & 1) * 4;
                pf[j] = *(const float4*)(xr + off);
            }
        }

        // ---- MFMA: 4 k-chunks x 8 col-tiles (8 independent chains) ----
        i32x4 acc[8];
#pragma unroll
        for (int t = 0; t < 8; ++t) acc[t] = (i32x4){0, 0, 0, 0};
#pragma unroll
        for (int kc = 0; kc < 4; ++kc)
#pragma unroll
            for (int t = 0; t < 8; ++t)
                acc[t] = __builtin_amdgcn_mfma_i32_16x16x32_i8(
                    afrag[kc], bfrag[t][kc], acc[t], 0, 0, 0);

        // ---- stats: S1 free from col 120; S2 via 16-lane butterfly ----
        int S2[4] = {0, 0, 0, 0};
#pragma unroll
        for (int t = 0; t < 8; ++t)
#pragma unroll
            for (int q = 0; q < 4; ++q) {
                int y = acc[t][q];
                if (t == 7) y = (l15 == 8) ? 0 : y;   // exclude S1 col from S2
                S2[q] += y * y;
            }
#pragma unroll
        for (int m = 1; m <= 8; m <<= 1)
#pragma unroll
            for (int q = 0; q < 4; ++q)
                S2[q] += __shfl_xor(S2[q], m, 64);

        float rstd[4], nb[4];
#pragma unroll
        for (int q = 0; q < 4; ++q) {
            const int s1 = __shfl(acc[7][q], (lane & 48) | 8, 64);  // col 120
            const float mean = (float)s1 * (1.0f / 120.0f);
            const float var  = (float)S2[q] * (1.0f / 120.0f) - mean * mean;
            rstd[q] = __builtin_amdgcn_rsqf(var + 1e-5f);
            nb[q]   = -mean * rstd[q];
        }

        // ---- epilogue: norm + affine + softsign + lin_w dot ----
        float d[4] = {0.0f, 0.0f, 0.0f, 0.0f};
#pragma unroll
        for (int t = 0; t < 8; ++t) {
            const float4 cf = s_cf[t * 16 + l15];
#pragma unroll
            for (int q = 0; q < 4; ++q) {
                const float yf = (float)acc[t][q] + cf.x;      // + conv_b
                const float n  = fmaf(yf, rstd[q], nb[q]);     // groupnorm
                const float g  = fmaf(n, cf.y, cf.z);          // *gn_w+gn_b
                const float s  = g * __builtin_amdgcn_rcpf(1.0f + fabsf(g));
                d[q] = fmaf(s, cf.w, d[q]);                    // dot lin_w
            }
        }
#pragma unroll
        for (int m = 1; m <= 8; m <<= 1)
#pragma unroll
            for (int q = 0; q < 4; ++q)
                d[q] += __shfl_xor(d[q], m, 64);

        if (l15 == 0) {
#pragma unroll
            for (int q = 0; q < 4; ++q) {
                const long long o = s0 + lg * 4 + q;           // row=lg*4+q
                if (o < (long long)B) out[o] = d[q];
            }
        }
    }
}

extern "C" void kernel_launch(void* const* d_in, const int* in_sizes, int n_in,
                              void* d_out, int out_size, void* d_ws, size_t ws_size,
                              hipStream_t stream) {
    const float* x      = (const float*)d_in[0];
    const float* conv_w = (const float*)d_in[1];
    const float* conv_b = (const float*)d_in[2];
    const float* gn_w   = (const float*)d_in[3];
    const float* gn_b   = (const float*)d_in[4];
    const float* lin_w  = (const float*)d_in[5];
    unsigned char* wsb = (unsigned char*)d_ws;
    float* out = (float*)d_out;

    const int B = in_sizes[0] / NCH;
    prep_kernel<<<1, 128, 0, stream>>>(conv_w, conv_b, gn_w, gn_b, lin_w, wsb);

    const int num_tiles = (B + 63) / 64;
    const int grid = num_tiles < 2048 ? num_tiles : 2048;
    const int tiles_per_block = (num_tiles + grid - 1) / grid;
    bnn_kernel<<<grid, 256, 0, stream>>>(x, wsb, out, B, num_tiles, tiles_per_block);
}

// Round 7
// 143.365 us; speedup vs baseline: 6.0146x; 6.0146x over previous
//
#include <hip/hip_runtime.h>

#define NCH 120

typedef int i32x4 __attribute__((ext_vector_type(4)));

// ---------------------------------------------------------------------------
// Prep kernel (1 block, 128 threads), two-phase:
//  phase 1: rows 0..119 of wb_i8[128][128] = sign(conv_w) in {-1,0,+1};
//           rows 120..127 zeroed.  (each thread owns one row, parallel)
//  phase 2: row 120 byte k = wsum[k] = sum_c sign(conv_w[c][k]) -- computed
//           by thread k from the PHASE-1 OUTPUT (120 parallel byte loads per
//           lane, not 14400 serial loads on one lane like R6's version).
//  coef[128] float4 = {conv_b, gn_w, gn_b, lin_w}; pads {0,1,0,0}.
//  ws layout: [0,16384) wb_i8; [16384,18432) coef.
// ---------------------------------------------------------------------------
__global__ void prep_kernel(const float* __restrict__ conv_w,
                            const float* __restrict__ conv_b,
                            const float* __restrict__ gn_w,
                            const float* __restrict__ gn_b,
                            const float* __restrict__ lin_w,
                            unsigned char* __restrict__ wsb)
{
    const int c = threadIdx.x;            // 0..127
    if (c >= 128) return;
    unsigned* row32 = (unsigned*)(wsb + c * 128);
    if (c < NCH) {
        for (int kw = 0; kw < 32; ++kw) {
            unsigned pk = 0u;
            for (int b = 0; b < 4; ++b) {
                const int k = kw * 4 + b;
                unsigned v = 0u;
                if (k < NCH) {
                    const float w = conv_w[c * NCH + k];
                    v = (w > 0.0f) ? 0x01u : ((w < 0.0f) ? 0xFFu : 0x00u);
                }
                pk |= v << (8 * b);
            }
            row32[kw] = pk;
        }
    } else {
        for (int kw = 0; kw < 32; ++kw) row32[kw] = 0u;
    }
    __syncthreads();   // phase-1 global writes visible block-wide

    // phase 2: thread k sums column k of the binarized rows
    {
        int s = 0;
        if (c < NCH)
            for (int r = 0; r < NCH; ++r)
                s += (int)(signed char)wsb[r * 128 + c];
        // write after all reads of row 120's old value can't matter (row 120
        // was zeroed in phase 1 and is not read in phase 2's sum: r < 120)
        wsb[120 * 128 + c] = (unsigned char)((unsigned)s & 0xFFu);
    }

    float4 o;
    o.x = (c < NCH) ? conv_b[c] : 0.0f;
    o.y = (c < NCH) ? gn_w[c]   : 1.0f;
    o.z = (c < NCH) ? gn_b[c]   : 0.0f;
    o.w = (c < NCH) ? lin_w[c]  : 0.0f;
    ((float4*)(wsb + 16384))[c] = o;
}

// Binarize 4 floats against 0.5 into 4 packed i8 in {+1, 0, -1}.
// sign(x-0.5): +1 if x>0.5, -1 if x<0.5, 0 if x==0.5 exactly.
__device__ __forceinline__ unsigned cvt4(float4 v) {
    unsigned b0 = (v.x > 0.5f) ? 0x01u : ((v.x < 0.5f) ? 0xFFu : 0x00u);
    unsigned b1 = (v.y > 0.5f) ? 0x01u : ((v.y < 0.5f) ? 0xFFu : 0x00u);
    unsigned b2 = (v.z > 0.5f) ? 0x01u : ((v.z < 0.5f) ? 0xFFu : 0x00u);
    unsigned b3 = (v.w > 0.5f) ? 0x01u : ((v.w < 0.5f) ? 0xFFu : 0x00u);
    return b0 | (b1 << 8) | (b2 << 16) | (b3 << 24);
}

// ---------------------------------------------------------------------------
// Main kernel, v7 == v6 (validated, ~95us): i8 MFMA binary GEMM +
// register prefetch + free S1 via wsum row (GEMM col 120).
//   A: lane holds A[l15][kc*32+lg*8+j]; B from wb[n][k] (row-major [N][K]);
//   C: row=lg*4+q, col=l15.  Exact integer path through stats.
// ---------------------------------------------------------------------------
__global__ __launch_bounds__(256) void bnn_kernel(
    const float* __restrict__ x,
    const unsigned char* __restrict__ wsb,
    float* __restrict__ out,
    int B, int num_tiles, int tiles_per_block)
{
    __shared__ float4 s_cf[128];

    const int tid  = threadIdx.x;
    const int lane = tid & 63;
    const int wv   = tid >> 6;
    const int l15  = lane & 15;
    const int lg   = lane >> 4;            // 0..3
    const bool padlane = (lg == 3);        // kc==3 chunk (k=120..127) is pad

    if (tid < 128) s_cf[tid] = ((const float4*)(wsb + 16384))[tid];
    __syncthreads();

    // ---- B fragments: loaded once, kept in VGPRs (8 col-tiles x 4 k-chunks)
    long bfrag[8][4];
#pragma unroll
    for (int t = 0; t < 8; ++t)
#pragma unroll
        for (int kc = 0; kc < 4; ++kc)
            bfrag[t][kc] = *(const long*)(wsb + (t * 16 + l15) * 128 + kc * 32 + lg * 8);

    // ---- prologue: prefetch first tile into pf ----
    float4 pf[8];
    {
        long long srow = (long long)blockIdx.x * 64 + wv * 16 + l15;
        if (srow > (long long)B - 1) srow = (long long)B - 1;
        const float* __restrict__ xr = x + srow * NCH;
#pragma unroll
        for (int j = 0; j < 8; ++j) {
            int off = (j >> 1) * 32 + lg * 8 + (j & 1) * 4;   // floats; 16B-aligned
            if (j >= 6 && padlane) off = (j & 1) * 4;          // pad chunk: safe dummy
            pf[j] = *(const float4*)(xr + off);
        }
    }

    for (int it = 0; it < tiles_per_block; ++it) {
        const int tile = blockIdx.x + it * gridDim.x;
        if (tile >= num_tiles) break;
        const long long s0 = (long long)tile * 64 + wv * 16;

        // ---- binarize the prefetched tile -> A fragments ----
        long afrag[4];
#pragma unroll
        for (int kc = 0; kc < 4; ++kc) {
            unsigned w0 = cvt4(pf[kc * 2]);
            unsigned w1 = cvt4(pf[kc * 2 + 1]);
            if (kc == 3 && padlane) { w0 = 0u; w1 = 0u; }
            afrag[kc] = (long)(((unsigned long long)w1 << 32) | w0);
        }

        // ---- prefetch NEXT tile (overlaps MFMA + epilogue below) ----
        if (it + 1 < tiles_per_block) {
            int nt = blockIdx.x + (it + 1) * gridDim.x;
            if (nt > num_tiles - 1) nt = num_tiles - 1;
            long long srow = (long long)nt * 64 + wv * 16 + l15;
            if (srow > (long long)B - 1) srow = (long long)B - 1;
            const float* __restrict__ xr = x + srow * NCH;
#pragma unroll
            for (int j = 0; j < 8; ++j) {
                int off = (j >> 1) * 32 + lg * 8 + (j & 1) * 4;
                if (j >= 6 && padlane) off = (j & 1) * 4;
                pf[j] = *(const float4*)(xr + off);
            }
        }

        // ---- MFMA: 4 k-chunks x 8 col-tiles (8 independent chains) ----
        i32x4 acc[8];
#pragma unroll
        for (int t = 0; t < 8; ++t) acc[t] = (i32x4){0, 0, 0, 0};
#pragma unroll
        for (int kc = 0; kc < 4; ++kc)
#pragma unroll
            for (int t = 0; t < 8; ++t)
                acc[t] = __builtin_amdgcn_mfma_i32_16x16x32_i8(
                    afrag[kc], bfrag[t][kc], acc[t], 0, 0, 0);

        // ---- stats: S1 free from col 120; S2 via 16-lane butterfly ----
        int S2[4] = {0, 0, 0, 0};
#pragma unroll
        for (int t = 0; t < 8; ++t)
#pragma unroll
            for (int q = 0; q < 4; ++q) {
                int y = acc[t][q];
                if (t == 7) y = (l15 == 8) ? 0 : y;   // exclude S1 col from S2
                S2[q] += y * y;
            }
#pragma unroll
        for (int m = 1; m <= 8; m <<= 1)
#pragma unroll
            for (int q = 0; q < 4; ++q)
                S2[q] += __shfl_xor(S2[q], m, 64);

        float rstd[4], nb[4];
#pragma unroll
        for (int q = 0; q < 4; ++q) {
            const int s1 = __shfl(acc[7][q], (lane & 48) | 8, 64);  // col 120
            const float mean = (float)s1 * (1.0f / 120.0f);
            const float var  = (float)S2[q] * (1.0f / 120.0f) - mean * mean;
            rstd[q] = __builtin_amdgcn_rsqf(var + 1e-5f);
            nb[q]   = -mean * rstd[q];
        }

        // ---- epilogue: norm + affine + softsign + lin_w dot ----
        float d[4] = {0.0f, 0.0f, 0.0f, 0.0f};
#pragma unroll
        for (int t = 0; t < 8; ++t) {
            const float4 cf = s_cf[t * 16 + l15];
#pragma unroll
            for (int q = 0; q < 4; ++q) {
                const float yf = (float)acc[t][q] + cf.x;      // + conv_b
                const float n  = fmaf(yf, rstd[q], nb[q]);     // groupnorm
                const float g  = fmaf(n, cf.y, cf.z);          // *gn_w+gn_b
                const float s  = g * __builtin_amdgcn_rcpf(1.0f + fabsf(g));
                d[q] = fmaf(s, cf.w, d[q]);                    // dot lin_w
            }
        }
#pragma unroll
        for (int m = 1; m <= 8; m <<= 1)
#pragma unroll
            for (int q = 0; q < 4; ++q)
                d[q] += __shfl_xor(d[q], m, 64);

        if (l15 == 0) {
#pragma unroll
            for (int q = 0; q < 4; ++q) {
                const long long o = s0 + lg * 4 + q;           // row=lg*4+q
                if (o < (long long)B) out[o] = d[q];
            }
        }
    }
}

extern "C" void kernel_launch(void* const* d_in, const int* in_sizes, int n_in,
                              void* d_out, int out_size, void* d_ws, size_t ws_size,
                              hipStream_t stream) {
    const float* x      = (const float*)d_in[0];
    const float* conv_w = (const float*)d_in[1];
    const float* conv_b = (const float*)d_in[2];
    const float* gn_w   = (const float*)d_in[3];
    const float* gn_b   = (const float*)d_in[4];
    const float* lin_w  = (const float*)d_in[5];
    unsigned char* wsb = (unsigned char*)d_ws;
    float* out = (float*)d_out;

    const int B = in_sizes[0] / NCH;
    prep_kernel<<<1, 128, 0, stream>>>(conv_w, conv_b, gn_w, gn_b, lin_w, wsb);

    const int num_tiles = (B + 63) / 64;
    const int grid = num_tiles < 2048 ? num_tiles : 2048;
    const int tiles_per_block = (num_tiles + grid - 1) / grid;
    bnn_kernel<<<grid, 256, 0, stream>>>(x, wsb, out, B, num_tiles, tiles_per_block);
}